// Round 15
// baseline (441.553 us; speedup 1.0000x reference)
//
#include <hip/hip_runtime.h>
#include <cmath>

#define DI __device__ __forceinline__

constexpr int B_=2, S_=2048, E_=1024, H_=1344, NH_=4, DH_=336;
constexpr int BS_=B_*S_, H2_=2*H_;
constexpr int NG_=B_*NH_*S_;   // 16384

constexpr size_t N_X=(size_t)BS_*E_;
constexpr size_t N_WUP=(size_t)E_*H2_;
constexpr size_t N_WDN=(size_t)H_*E_;
constexpr size_t N_BSH=(size_t)BS_*H_;
constexpr size_t N_BSH2=(size_t)BS_*H2_;
constexpr size_t N_WH=5376, N_WG=16128, N_CK=4*H_;

// ---- ws layout (floats); identical to prior passing rounds ----
constexpr size_t O_IGB = 64;
constexpr size_t O_LOGF= O_IGB + NG_;
constexpr size_t O_AB  = O_LOGF+ NG_;
constexpr size_t O_MB  = O_AB  + NG_;
constexpr size_t O_MTB = O_MB  + NG_;
constexpr size_t O_CK  = O_MTB + NG_;
constexpr size_t O_CB  = O_CK  + N_CK;
constexpr size_t O_WQ  = O_CB  + H_;
constexpr size_t O_WK  = O_WQ  + N_WH;
constexpr size_t O_WV  = O_WK  + N_WH;
constexpr size_t O_WIG = O_WV  + N_WH;
constexpr size_t O_BIG = O_WIG + N_WG;
constexpr size_t O_WFG = O_BIG + 16;
constexpr size_t O_BFG = O_WFG + N_WG;
constexpr size_t O_LNW = O_BFG + 16;
constexpr size_t O_SKP = O_LNW + H_;
constexpr size_t O_FX  = O_SKP + H_;
constexpr size_t O_FWUP= O_FX  + N_X;
constexpr size_t O_FWDN= O_FWUP+ N_WUP;
constexpr size_t O_XIN = O_FWDN+ N_WDN;
constexpr size_t O_ACT = O_XIN + N_BSH2;
constexpr size_t O_QB  = O_ACT + N_BSH;
constexpr size_t O_KB  = O_QB  + N_BSH;
constexpr size_t O_VB  = O_KB  + N_BSH;
constexpr size_t O_HOUT= O_VB  + N_BSH;

// khi/klo: [head][tile=t/16][dc=0..10][l][8] bf16 (B-frag 16x16x32)
constexpr size_t KSPLIT_SHORTS=(size_t)8*128*11*64*8;  // 5,767,168
// vTf: [head][tc=t/32][ntg=0..21][l][8] bf16; n==336 -> 1.0 (rowsum), n>336 -> 0
constexpr size_t VT_SHORTS=(size_t)8*64*22*64*8;       // 5,767,168

typedef __attribute__((ext_vector_type(8))) short bf16x8;
typedef __attribute__((ext_vector_type(4))) float f32x4;

DI float bf2f(unsigned int u){union{unsigned int i;float f;}v;v.i=(u&0xffffu)<<16;return v.f;}
DI unsigned short f2bf(float f){union{float f;unsigned int i;}v;v.f=f;unsigned int x=v.i;
  return (unsigned short)((x+0x7fffu+((x>>16)&1u))>>16);}
DI float siluf(float x){return x/(1.f+expf(-x));}
DI float logsigf(float x){return (x>=0.f)?-log1pf(expf(-x)):x-log1pf(expf(x));}
DI void load4(const float* p, float* d){float4 v=*reinterpret_cast<const float4*>(p);
  d[0]=v.x;d[1]=v.y;d[2]=v.z;d[3]=v.w;}

// ---- dtype detect (fp32 proven; keep the guard) ----
__global__ __launch_bounds__(256) void detect_k(const unsigned short* __restrict__ xraw,
                                                int* __restrict__ flag){
  __shared__ int cnt_s;
  if(threadIdx.x==0) cnt_s=0;
  __syncthreads();
  int c=0;
  for(int i=threadIdx.x;i<2048;i+=256){
    const unsigned e=(xraw[i]>>7)&0xFFu;
    if(e>=0x90u) c++;
  }
  atomicAdd(&cnt_s,c);
  __syncthreads();
  if(threadIdx.x==0) *flag=(cnt_s>16)?0:1;
}

constexpr int CV0=5376, CV1=CV0+1344, CV2=CV1+5376, CV3=CV2+5376, CV4=CV3+5376,
              CV5=CV4+16128, CV6=CV5+4, CV7=CV6+16128, CV8=CV7+4,
              CV9=CV8+1344, CVT=CV9+1344;     // 57800 total

// ============================================================================
// MERGED prep: blk<2048 -> x A-frags; blk<3392 -> Wup B-frags; else convall
// tail (11 small weight tensors -> ws fp32). All read *flag.
// ============================================================================
__global__ __launch_bounds__(256) void prepAB_k(const void* __restrict__ xsrc,
    const void* __restrict__ wsrc, const int* __restrict__ flag,
    unsigned short* __restrict__ xhi, unsigned short* __restrict__ xlo,
    unsigned short* __restrict__ whi, unsigned short* __restrict__ wlo,
    const void* s2,const void* s3,const void* s4,const void* s5,const void* s6,
    const void* s7,const void* s8,const void* s9,const void* s10,const void* s11,
    const void* s12, float* __restrict__ ws){
  const int blk=blockIdx.x;
  const int fl=*flag;
  if(blk>=3392){
    const int i=(blk-3392)*256+threadIdx.x;
    if(i>=CVT) return;
    const void* src; int off; size_t dst;
    if(i<CV0){src=s2; off=i;      dst=O_CK +off;}
    else if(i<CV1){src=s3; off=i-CV0; dst=O_CB +off;}
    else if(i<CV2){src=s4; off=i-CV1; dst=O_WQ +off;}
    else if(i<CV3){src=s5; off=i-CV2; dst=O_WK +off;}
    else if(i<CV4){src=s6; off=i-CV3; dst=O_WV +off;}
    else if(i<CV5){src=s7; off=i-CV4; dst=O_WIG+off;}
    else if(i<CV6){src=s8; off=i-CV5; dst=O_BIG+off;}
    else if(i<CV7){src=s9; off=i-CV6; dst=O_WFG+off;}
    else if(i<CV8){src=s10;off=i-CV7; dst=O_BFG+off;}
    else if(i<CV9){src=s11;off=i-CV8; dst=O_LNW+off;}
    else          {src=s12;off=i-CV9; dst=O_SKP+off;}
    ws[dst]=fl?bf2f(((const unsigned short*)src)[off])
              :((const float*)src)[off];
    return;
  }
  float v[8];
  unsigned short* dh; unsigned short* dl; size_t slot;
  if(blk<2048){
    slot=(size_t)blk*256+threadIdx.x;       // exactly 524288 = 256*32*64
    const int l=(int)slot&63, rest=(int)(slot>>6);
    const int kc=rest&31, mt=rest>>5;
    const int row=mt*16+(l&15), k0=kc*32+(l>>4)*8;
    if(fl){
      const unsigned short* s=(const unsigned short*)xsrc+(size_t)row*1024+k0;
      const uint4 u=*reinterpret_cast<const uint4*>(s);
      v[0]=bf2f(u.x);v[1]=bf2f(u.x>>16);v[2]=bf2f(u.y);v[3]=bf2f(u.y>>16);
      v[4]=bf2f(u.z);v[5]=bf2f(u.z>>16);v[6]=bf2f(u.w);v[7]=bf2f(u.w>>16);
    }else{
      const float* s=(const float*)xsrc+(size_t)row*1024+k0;
      load4(s,v); load4(s+4,v+4);
    }
    dh=xhi; dl=xlo;
  } else {
    slot=(size_t)(blk-2048)*256+threadIdx.x; // exactly 344064 = 168*32*64
    const int l=(int)slot&63, rest=(int)(slot>>6);
    const int kc=rest&31, nt=rest>>5;
    const int col=nt*16+(l&15), row0=kc*32+(l>>4)*8;
    if(fl){
      const unsigned short* s=(const unsigned short*)wsrc;
#pragma unroll
      for(int j=0;j<8;j++) v[j]=bf2f(s[(size_t)(row0+j)*2688+col]);
    }else{
      const float* s=(const float*)wsrc;
#pragma unroll
      for(int j=0;j<8;j++) v[j]=s[(size_t)(row0+j)*2688+col];
    }
    dh=whi; dl=wlo;
  }
  unsigned short h8[8], l8[8];
#pragma unroll
  for(int j=0;j<8;j++){ h8[j]=f2bf(v[j]); l8[j]=f2bf(v[j]-bf2f(h8[j])); }
  uint4 ph,pl;
  ph.x=(unsigned)h8[0]|((unsigned)h8[1]<<16); ph.y=(unsigned)h8[2]|((unsigned)h8[3]<<16);
  ph.z=(unsigned)h8[4]|((unsigned)h8[5]<<16); ph.w=(unsigned)h8[6]|((unsigned)h8[7]<<16);
  pl.x=(unsigned)l8[0]|((unsigned)l8[1]<<16); pl.y=(unsigned)l8[2]|((unsigned)l8[3]<<16);
  pl.z=(unsigned)l8[4]|((unsigned)l8[5]<<16); pl.w=(unsigned)l8[6]|((unsigned)l8[7]<<16);
  *reinterpret_cast<uint4*>(&dh[slot*8])=ph;
  *reinterpret_cast<uint4*>(&dl[slot*8])=pl;
}

// ============================================================================
// GEMM v3: 128x128 tile, 4 waves, counted-vmcnt pipeline (passing). Up-GEMM.
// ============================================================================
__global__ __launch_bounds__(256) void gemm3_k(
    const unsigned short* __restrict__ Ahi, const unsigned short* __restrict__ Alo,
    const unsigned short* __restrict__ Bhi, const unsigned short* __restrict__ Blo,
    void* __restrict__ C, const int* __restrict__ flag, int kcn, int ldc){
  const int t=threadIdx.x, w=t>>6, l=t&63, lm=l&15, quad=l>>4;
  const int bn=blockIdx.x*128, bm=blockIdx.y*128;
  const int mtg0=bm>>4, ntg0=bn>>4;

  __shared__ short TT[2][32*512];           // [0-7]Ahi [8-15]Alo [16-23]Bhi [24-31]Blo

  f32x4 acc[2][8];
#pragma unroll
  for(int g=0;g<2;g++)
#pragma unroll
    for(int nt=0;nt<8;nt++) acc[g][nt]={0.f,0.f,0.f,0.f};

  auto stage=[&](int buf,int kc){
#pragma unroll
    for(int j=0;j<8;j++){
      const int tr=w*8+j;
      const unsigned short* src;
      if(tr<8)       src=&Ahi[((size_t)(mtg0+tr   )*kcn+kc)*512+(size_t)l*8];
      else if(tr<16) src=&Alo[((size_t)(mtg0+tr-8 )*kcn+kc)*512+(size_t)l*8];
      else if(tr<24) src=&Bhi[((size_t)(ntg0+tr-16)*kcn+kc)*512+(size_t)l*8];
      else           src=&Blo[((size_t)(ntg0+tr-24)*kcn+kc)*512+(size_t)l*8];
      __builtin_amdgcn_global_load_lds(
        (const __attribute__((address_space(1))) unsigned int*)src,
        (__attribute__((address_space(3))) unsigned int*)&TT[buf][tr*512],
        16,0,0);
    }
  };

  auto compute=[&](int buf){
    const short* Tb=&TT[buf][0];
    const bf16x8 ah0=*reinterpret_cast<const bf16x8*>(&Tb[(2*w  )*512+l*8]);
    const bf16x8 ah1=*reinterpret_cast<const bf16x8*>(&Tb[(2*w+1)*512+l*8]);
    const bf16x8 al0=*reinterpret_cast<const bf16x8*>(&Tb[(8+2*w  )*512+l*8]);
    const bf16x8 al1=*reinterpret_cast<const bf16x8*>(&Tb[(8+2*w+1)*512+l*8]);
#pragma unroll
    for(int nt=0;nt<8;nt++){
      const bf16x8 bh=*reinterpret_cast<const bf16x8*>(&Tb[(16+nt)*512+l*8]);
      const bf16x8 bl=*reinterpret_cast<const bf16x8*>(&Tb[(24+nt)*512+l*8]);
      acc[0][nt]=__builtin_amdgcn_mfma_f32_16x16x32_bf16(ah0,bh,acc[0][nt],0,0,0);
      acc[0][nt]=__builtin_amdgcn_mfma_f32_16x16x32_bf16(al0,bh,acc[0][nt],0,0,0);
      acc[0][nt]=__builtin_amdgcn_mfma_f32_16x16x32_bf16(ah0,bl,acc[0][nt],0,0,0);
      acc[1][nt]=__builtin_amdgcn_mfma_f32_16x16x32_bf16(ah1,bh,acc[1][nt],0,0,0);
      acc[1][nt]=__builtin_amdgcn_mfma_f32_16x16x32_bf16(al1,bh,acc[1][nt],0,0,0);
      acc[1][nt]=__builtin_amdgcn_mfma_f32_16x16x32_bf16(ah1,bl,acc[1][nt],0,0,0);
    }
  };

  stage(0,0);
  for(int kc=0;kc<kcn;kc++){
    const int cur=kc&1;
    if(kc+1<kcn){
      stage(cur^1,kc+1);                    // prefetch stays in flight
      asm volatile("s_waitcnt vmcnt(8)" ::: "memory");   // wait prev 8 only
    } else {
      asm volatile("s_waitcnt vmcnt(0)" ::: "memory");
    }
    __builtin_amdgcn_s_barrier();           // all waves' cur-step loads landed
    compute(cur);
    __builtin_amdgcn_s_barrier();           // protect buffer overwrite
  }

  const int bf=flag?*flag:0;
#pragma unroll
  for(int g=0;g<2;g++)
#pragma unroll
    for(int nt=0;nt<8;nt++)
#pragma unroll
      for(int r=0;r<4;r++){
        const size_t idx=(size_t)(bm+(2*w+g)*16+quad*4+r)*ldc+bn+nt*16+lm;
        if(bf) ((unsigned short*)C)[idx]=f2bf(acc[g][nt][r]);
        else   ((float*)C)[idx]=acc[g][nt][r];
      }
}

// ============================================================================
// GEMM v4: 128x64 tile (down-GEMM occupancy fix: 512 blocks -> all 256 CUs
// at 2 blocks/CU, vs 256 blocks = half machine with the 128x128 tile).
// Same counted-vmcnt pipeline; per k-step 24 tiles (8Ahi,8Alo,4Bhi,4Blo);
// per wave 2mt x 4nt x 3-chain = 24 MFMA. Numerics identical.
// ============================================================================
__global__ __launch_bounds__(256) void gemm4_k(
    const unsigned short* __restrict__ Ahi, const unsigned short* __restrict__ Alo,
    const unsigned short* __restrict__ Bhi, const unsigned short* __restrict__ Blo,
    void* __restrict__ C, const int* __restrict__ flag, int kcn, int ldc){
  const int t=threadIdx.x, w=t>>6, l=t&63, lm=l&15, quad=l>>4;
  const int bn=blockIdx.x*64, bm=blockIdx.y*128;
  const int mtg0=bm>>4, ntg0=bn>>4;

  __shared__ short TT[2][24*512];           // [0-7]Ahi [8-15]Alo [16-19]Bhi [20-23]Blo

  f32x4 acc[2][4];
#pragma unroll
  for(int g=0;g<2;g++)
#pragma unroll
    for(int nt=0;nt<4;nt++) acc[g][nt]={0.f,0.f,0.f,0.f};

  auto stage=[&](int buf,int kc){
#pragma unroll
    for(int j=0;j<6;j++){
      const int tr=w*6+j;
      const unsigned short* src;
      if(tr<8)       src=&Ahi[((size_t)(mtg0+tr   )*kcn+kc)*512+(size_t)l*8];
      else if(tr<16) src=&Alo[((size_t)(mtg0+tr-8 )*kcn+kc)*512+(size_t)l*8];
      else if(tr<20) src=&Bhi[((size_t)(ntg0+tr-16)*kcn+kc)*512+(size_t)l*8];
      else           src=&Blo[((size_t)(ntg0+tr-20)*kcn+kc)*512+(size_t)l*8];
      __builtin_amdgcn_global_load_lds(
        (const __attribute__((address_space(1))) unsigned int*)src,
        (__attribute__((address_space(3))) unsigned int*)&TT[buf][tr*512],
        16,0,0);
    }
  };

  auto compute=[&](int buf){
    const short* Tb=&TT[buf][0];
    const bf16x8 ah0=*reinterpret_cast<const bf16x8*>(&Tb[(2*w  )*512+l*8]);
    const bf16x8 ah1=*reinterpret_cast<const bf16x8*>(&Tb[(2*w+1)*512+l*8]);
    const bf16x8 al0=*reinterpret_cast<const bf16x8*>(&Tb[(8+2*w  )*512+l*8]);
    const bf16x8 al1=*reinterpret_cast<const bf16x8*>(&Tb[(8+2*w+1)*512+l*8]);
#pragma unroll
    for(int nt=0;nt<4;nt++){
      const bf16x8 bh=*reinterpret_cast<const bf16x8*>(&Tb[(16+nt)*512+l*8]);
      const bf16x8 bl=*reinterpret_cast<const bf16x8*>(&Tb[(20+nt)*512+l*8]);
      acc[0][nt]=__builtin_amdgcn_mfma_f32_16x16x32_bf16(ah0,bh,acc[0][nt],0,0,0);
      acc[0][nt]=__builtin_amdgcn_mfma_f32_16x16x32_bf16(al0,bh,acc[0][nt],0,0,0);
      acc[0][nt]=__builtin_amdgcn_mfma_f32_16x16x32_bf16(ah0,bl,acc[0][nt],0,0,0);
      acc[1][nt]=__builtin_amdgcn_mfma_f32_16x16x32_bf16(ah1,bh,acc[1][nt],0,0,0);
      acc[1][nt]=__builtin_amdgcn_mfma_f32_16x16x32_bf16(al1,bh,acc[1][nt],0,0,0);
      acc[1][nt]=__builtin_amdgcn_mfma_f32_16x16x32_bf16(ah1,bl,acc[1][nt],0,0,0);
    }
  };

  stage(0,0);
  for(int kc=0;kc<kcn;kc++){
    const int cur=kc&1;
    if(kc+1<kcn){
      stage(cur^1,kc+1);                    // prefetch stays in flight
      asm volatile("s_waitcnt vmcnt(6)" ::: "memory");   // wait prev 6 only
    } else {
      asm volatile("s_waitcnt vmcnt(0)" ::: "memory");
    }
    __builtin_amdgcn_s_barrier();           // all waves' cur-step loads landed
    compute(cur);
    __builtin_amdgcn_s_barrier();           // protect buffer overwrite
  }

  const int bf=flag?*flag:0;
#pragma unroll
  for(int g=0;g<2;g++)
#pragma unroll
    for(int nt=0;nt<4;nt++)
#pragma unroll
      for(int r=0;r<4;r++){
        const size_t idx=(size_t)(bm+(2*w+g)*16+quad*4+r)*ldc+bn+nt*16+lm;
        if(bf) ((unsigned short*)C)[idx]=f2bf(acc[g][nt][r]);
        else   ((float*)C)[idx]=acc[g][nt][r];
      }
}

// ============================================================================
// FUSED conv_act + qkv + gates + DIRECT K-frag emit (passing, round 14).
// ============================================================================
__global__ __launch_bounds__(384) void convqkvgates_k(
    const float* __restrict__ xin, const float* __restrict__ ck,
    const float* __restrict__ cb,
    const float* __restrict__ Wq, const float* __restrict__ Wk,
    const float* __restrict__ Wv,
    const float* __restrict__ Wig, const float* __restrict__ big,
    const float* __restrict__ Wfg, const float* __restrict__ bfg,
    float* __restrict__ act, float* __restrict__ qb, float* __restrict__ vb,
    unsigned short* __restrict__ khi, unsigned short* __restrict__ klo,
    float* __restrict__ igb, float* __restrict__ logfb){
  const int bs=blockIdx.x;
  const int b=bs>>11, s=bs&2047;
  const int t=threadIdx.x;
  __shared__ float4 sq4[336], sk4[336], sv4[336];
  __shared__ float red[6][8];
  if(t<336){
    const int ph=t, base=ph*4;
    float xc[4];
#pragma unroll
    for(int d=0;d<4;d++) xc[d]=cb[base+d];
    float xm[4]={0.f,0.f,0.f,0.f};
#pragma unroll
    for(int w=0;w<4;w++){
      const int sr=s-3+w;
      if(sr>=0){
        float xv[4];
        load4(&xin[(size_t)(b*S_+sr)*H2_+base],xv);
#pragma unroll
        for(int d=0;d<4;d++) xc[d]+=xv[d]*ck[w*H_+base+d];
        if(w==3){ xm[0]=xv[0];xm[1]=xv[1];xm[2]=xv[2];xm[3]=xv[3]; }
      }
    }
    float a4[4];
#pragma unroll
    for(int d=0;d<4;d++) a4[d]=siluf(xc[d]);
    *reinterpret_cast<float4*>(&act[(size_t)bs*H_+base])
        =make_float4(a4[0],a4[1],a4[2],a4[3]);
    float q4[4],k4[4],v4[4];
#pragma unroll
    for(int o=0;o<4;o++){
      float q=0.f,k=0.f,v=0.f;
#pragma unroll
      for(int d=0;d<4;d++){
        q+=a4[d]*Wq[ph*16+d*4+o];
        k+=a4[d]*Wk[ph*16+d*4+o];
        v+=xm[d]*Wv[ph*16+d*4+o];
      }
      q4[o]=q;k4[o]=k;v4[o]=v;
    }
    const int nh=ph/84, dh0=(ph-nh*84)*4;   // 4 outputs stay in one head
    const size_t off=((size_t)(b*NH_+nh)*S_+s)*DH_+dh0;
    *reinterpret_cast<float4*>(&qb[off])=make_float4(q4[0],q4[1],q4[2],q4[3]);
    *reinterpret_cast<float4*>(&vb[off])=make_float4(v4[0],v4[1],v4[2],v4[3]);
    // direct K-frag emit (hi/lo), replacing the kb round-trip
    {
      const int head8=b*NH_+nh;
      const int tt=s>>4, lm=s&15;
      const int dc=dh0>>5, quad=(dh0&31)>>3, j=dh0&7;  // j in {0,4}
      const size_t ob=(((size_t)(head8*128+tt)*11)+dc)*512
                      +(size_t)(quad*16+lm)*8+j;
      unsigned short kh[4], kl[4];
#pragma unroll
      for(int o=0;o<4;o++){
        kh[o]=f2bf(k4[o]);
        kl[o]=f2bf(k4[o]-bf2f(kh[o]));
      }
      uint2 pk, pl;
      pk.x=(unsigned)kh[0]|((unsigned)kh[1]<<16);
      pk.y=(unsigned)kh[2]|((unsigned)kh[3]<<16);
      pl.x=(unsigned)kl[0]|((unsigned)kl[1]<<16);
      pl.y=(unsigned)kl[2]|((unsigned)kl[3]<<16);
      *reinterpret_cast<uint2*>(&khi[ob])=pk;
      *reinterpret_cast<uint2*>(&klo[ob])=pl;
    }
    sq4[ph]=make_float4(q4[0],q4[1],q4[2],q4[3]);
    sk4[ph]=make_float4(k4[0],k4[1],k4[2],k4[3]);
    sv4[ph]=make_float4(v4[0],v4[1],v4[2],v4[3]);
  }
  __syncthreads();
  const float* sq=reinterpret_cast<const float*>(sq4);
  const float* sk=reinterpret_cast<const float*>(sk4);
  const float* sv=reinterpret_cast<const float*>(sv4);
  float aI0=0.f,aI1=0.f,aI2=0.f,aI3=0.f;
  float aF0=0.f,aF1=0.f,aF2=0.f,aF3=0.f;
  for(int h=t; h<H_; h+=384){
    const float q=sq[h], k=sk[h], v=sv[h];
    const float4 wiq=*reinterpret_cast<const float4*>(&Wig[(size_t)h*4]);
    const float4 wik=*reinterpret_cast<const float4*>(&Wig[(size_t)(H_+h)*4]);
    const float4 wiv=*reinterpret_cast<const float4*>(&Wig[(size_t)(2*H_+h)*4]);
    const float4 wfq=*reinterpret_cast<const float4*>(&Wfg[(size_t)h*4]);
    const float4 wfk=*reinterpret_cast<const float4*>(&Wfg[(size_t)(H_+h)*4]);
    const float4 wfv=*reinterpret_cast<const float4*>(&Wfg[(size_t)(2*H_+h)*4]);
    aI0+=q*wiq.x+k*wik.x+v*wiv.x;
    aI1+=q*wiq.y+k*wik.y+v*wiv.y;
    aI2+=q*wiq.z+k*wik.z+v*wiv.z;
    aI3+=q*wiq.w+k*wik.w+v*wiv.w;
    aF0+=q*wfq.x+k*wfk.x+v*wfv.x;
    aF1+=q*wfq.y+k*wfk.y+v*wfv.y;
    aF2+=q*wfq.z+k*wfk.z+v*wfv.z;
    aF3+=q*wfq.w+k*wfk.w+v*wfv.w;
  }
#pragma unroll
  for(int m=1;m<64;m<<=1){
    aI0+=__shfl_xor(aI0,m); aI1+=__shfl_xor(aI1,m);
    aI2+=__shfl_xor(aI2,m); aI3+=__shfl_xor(aI3,m);
    aF0+=__shfl_xor(aF0,m); aF1+=__shfl_xor(aF1,m);
    aF2+=__shfl_xor(aF2,m); aF3+=__shfl_xor(aF3,m);
  }
  const int wv=t>>6, l=t&63;
  if(l==0){
    red[wv][0]=aI0; red[wv][1]=aI1; red[wv][2]=aI2; red[wv][3]=aI3;
    red[wv][4]=aF0; red[wv][5]=aF1; red[wv][6]=aF2; red[wv][7]=aF3;
  }
  __syncthreads();
  if(t==0){
    float r[8];
#pragma unroll
    for(int j=0;j<8;j++){
      float a=0.f;
#pragma unroll
      for(int wv2=0;wv2<6;wv2++) a+=red[wv2][j];
      r[j]=a;
    }
#pragma unroll
    for(int n=0;n<4;n++){
      const size_t o=(size_t)(b*NH_+n)*S_+s;
      igb[o]=r[n]+big[n];
      logfb[o]=logsigf(r[4+n]+bfg[n]);
    }
  }
}

// ============================================================================
// MERGED V/Wdn prep + K-pad zero + SCAN. blk<512: V frags + part-zero fold.
// blk<1184: Wdn B-frags. blk<1248 (64): K-frag pad zero. blk>=1248 (8):
// per-head scan + rsum-zero fold (igb/logfb ready: convqkvgates precedes).
// ============================================================================
__global__ __launch_bounds__(256) void vwprep_k(const float* vb,
                                                const void* __restrict__ wdnsrc,
                                                const int* __restrict__ flag,
                                                unsigned short* __restrict__ vTf,
                                                unsigned short* __restrict__ wdnhi,
                                                unsigned short* __restrict__ wdnlo,
                                                unsigned short* __restrict__ khi,
                                                unsigned short* __restrict__ klo,
                                                float* partz,
                                                float* igm,
                                                const float* __restrict__ logfb,
                                                float* __restrict__ ab,
                                                float* __restrict__ Mb,
                                                float* __restrict__ mtb){
  const int blk=blockIdx.x;
  if(blk<512){
    const int head=blk>>6, tc=blk&63;
    const size_t obase=(size_t)blk*22*512;
    for(int slot=threadIdx.x; slot<1408; slot+=256){
      const int ntg=slot>>6, ll=slot&63, quad=ll>>4, lm=ll&15;
      const int n=ntg*16+lm, t0=tc*32+quad*8;
      unsigned short h8[8];
#pragma unroll
      for(int j=0;j<8;j++){
        float val;
        if(n<336)       val=vb[((size_t)head*S_+t0+j)*DH_+n];
        else if(n==336) val=1.f;
        else            val=0.f;
        h8[j]=f2bf(val);
      }
      uint4 pk;
      pk.x=(unsigned)h8[0]|((unsigned)h8[1]<<16); pk.y=(unsigned)h8[2]|((unsigned)h8[3]<<16);
      pk.z=(unsigned)h8[4]|((unsigned)h8[5]<<16); pk.w=(unsigned)h8[6]|((unsigned)h8[7]<<16);
      *reinterpret_cast<uint4*>(&vTf[obase+(size_t)(ntg*64+ll)*8])=pk;
    }
    __syncthreads();                        // all reads of this slab done
    const size_t zb=((size_t)head*2048+(size_t)tc*32)*336;
    for(int idx=threadIdx.x; idx<32*336; idx+=256) partz[zb+idx]=0.f;
  } else if(blk<1184){
    const size_t slot=(size_t)(blk-512)*256+threadIdx.x;  // exact 172032
    const int l=(int)slot&63, rest=(int)(slot>>6);
    const int kc=rest%42, nt=rest/42;
    const int col=nt*16+(l&15), row0=kc*32+(l>>4)*8;
    const int fl=*flag;
    float v[8];
    if(fl){
      const unsigned short* s=(const unsigned short*)wdnsrc;
#pragma unroll
      for(int j=0;j<8;j++) v[j]=bf2f(s[(size_t)(row0+j)*1024+col]);
    }else{
      const float* s=(const float*)wdnsrc;
#pragma unroll
      for(int j=0;j<8;j++) v[j]=s[(size_t)(row0+j)*1024+col];
    }
    unsigned short h8[8], l8[8];
#pragma unroll
    for(int j=0;j<8;j++){ h8[j]=f2bf(v[j]); l8[j]=f2bf(v[j]-bf2f(h8[j])); }
    uint4 ph,pl;
    ph.x=(unsigned)h8[0]|((unsigned)h8[1]<<16); ph.y=(unsigned)h8[2]|((unsigned)h8[3]<<16);
    ph.z=(unsigned)h8[4]|((unsigned)h8[5]<<16); ph.w=(unsigned)h8[6]|((unsigned)h8[7]<<16);
    pl.x=(unsigned)l8[0]|((unsigned)l8[1]<<16); pl.y=(unsigned)l8[2]|((unsigned)l8[3]<<16);
    pl.z=(unsigned)l8[4]|((unsigned)l8[5]<<16); pl.w=(unsigned)l8[6]|((unsigned)l8[7]<<16);
    *reinterpret_cast<uint4*>(&wdnhi[slot*8])=ph;
    *reinterpret_cast<uint4*>(&wdnlo[slot*8])=pl;
  } else if(blk<1248){
    // K-pad zero: 1024 k-tiles, shorts [256,512) of the dc=10 sub-tile.
    const int idx=(blk-1184)*256+threadIdx.x;   // 0..16383
    const int kt=idx>>4, u=idx&15;
    const size_t base_s=(((size_t)kt*11)+10)*512 + 256 + (size_t)u*16;
    const uint4 z={0,0,0,0};
    *reinterpret_cast<uint4*>(&khi[base_s])=z;
    *reinterpret_cast<uint4*>(&klo[base_s])=z;
  } else {
    // per-head scan + rsum-zero fold (8 blocks)
    const int head=blk-1248, t=threadIdx.x;
    __shared__ float sh[256];
    const float* lf=logfb+(size_t)head*S_;
    float* ig=igm+(size_t)head*S_;
    float lc[8];
    float run=0.f;
#pragma unroll
    for(int i=0;i<8;i++){ run+=lf[t*8+i]; lc[i]=run; }
    sh[t]=run;
    for(int st=1;st<256;st<<=1){
      __syncthreads();
      const float v=(t>=st)?sh[t-st]:0.f;
      __syncthreads();
      sh[t]+=v;
    }
    __syncthreads();
    const float off=(t==0)?0.f:sh[t-1];
    __syncthreads();
    float av[8],mv[8],cv[8];
    float mrun=-1e30f;
#pragma unroll
    for(int i=0;i<8;i++){
      cv[i]=off+lc[i];
      av[i]=ig[t*8+i]-cv[i];
      mrun=fmaxf(mrun,av[i]);
      mv[i]=mrun;
    }
    sh[t]=mrun;
    for(int st=1;st<256;st<<=1){
      __syncthreads();
      const float v=(t>=st)?sh[t-st]:-1e30f;
      __syncthreads();
      sh[t]=fmaxf(sh[t],v);
    }
    __syncthreads();
    const float moff=(t==0)?-1e30f:sh[t-1];
#pragma unroll
    for(int i=0;i<8;i++){
      const float Mi=fmaxf(moff,mv[i]);
      const size_t j=(size_t)head*S_+t*8+i;
      ab[j]=av[i]; Mb[j]=Mi; mtb[j]=cv[i]+Mi;
      ig[t*8+i]=0.f;                        // rsum zero (same buffer, after read)
    }
  }
}

// ============================================================================
// mLSTM v12 (proven 113 µs) — 512 threads: 8 waves x 16 rows = 128-row
// supertiles, paired p<->15-p, 4-way seg: 256 blocks x 17 chunks.
// ============================================================================
__global__ __launch_bounds__(512,1) void mlstm6_k(
    const float* __restrict__ qb, const unsigned short* __restrict__ khi,
    const unsigned short* __restrict__ klo, const unsigned short* __restrict__ vTf,
    const float* __restrict__ ab, const float* __restrict__ Mb,
    float* __restrict__ part, float* __restrict__ rsum){
  const int bid=blockIdx.x;
  const int head=bid&7;                     // XCD pin: head h -> XCD h
  const int rest=bid>>3;                    // 0..31
  const int pairI=rest&7, seg=rest>>3;      // pair 0..7, seg 0..3
  const int t=threadIdx.x, w=t>>6, l=t&63, lm=l&15, quad=l>>4;

  __shared__ short KV[2][66*512];
  __shared__ short Sc[8][16][40];

  const size_t hb=(size_t)head*S_;
  const float scale=0.05455447256f;         // 336^-0.5

  const int sbA=pairI, sbB=15-pairI;        // 128-row supertiles
  const int nA=pairI+1, nTot=17;            // uniform work across all blocks

  bf16x8 qh[11], ql[11];
  f32x4 accO[22];
  float Mr[4];
  int ws0=sbA*128+w*16;

  auto loadQ=[&](int ws0_){
    const float* qrow=qb+(hb+ws0_+lm)*DH_;
#pragma unroll
    for(int dc=0;dc<11;dc++){
      const int dbase=dc*32+quad*8;
      float v[8];
      if(dbase<336){ load4(qrow+dbase,v); load4(qrow+dbase+4,v+4); }
      else { for(int j=0;j<8;j++) v[j]=0.f; }
#pragma unroll
      for(int j=0;j<8;j++){
        const unsigned short h=f2bf(v[j]);
        qh[dc][j]=(short)h;
        ql[dc][j]=(short)f2bf(v[j]-bf2f(h));
      }
    }
#pragma unroll
    for(int r=0;r<4;r++) Mr[r]=Mb[hb+ws0_+quad*4+r];
#pragma unroll
    for(int n=0;n<22;n++) accO[n]={0.f,0.f,0.f,0.f};
  };

  auto itemC=[&](int i)->int{
    return (i<nA)? (seg+4*i) : (seg+4*(i-nA));
  };

  auto stage=[&](int buf,int c){
    const size_t kbase=(((size_t)head*128+(size_t)(2*c))*11)*512+(size_t)l*8;
    const size_t vbase=(((size_t)head*64+(size_t)c)*22)*512+(size_t)l*8;
#pragma unroll
    for(int j=0;j<9;j++){
      const int tr=w+8*j;
      if(tr<66){
        const unsigned short* src;
        if(tr<22)      src=&khi[kbase+(size_t)tr*512];
        else if(tr<44) src=&klo[kbase+(size_t)(tr-22)*512];
        else           src=&vTf[vbase+(size_t)(tr-44)*512];
        __builtin_amdgcn_global_load_lds(
          (const __attribute__((address_space(1))) unsigned int*)src,
          (__attribute__((address_space(3))) unsigned int*)&KV[buf][(size_t)tr*512],
          16,0,0);
      }
    }
  };

  auto compute=[&](int c,int buf){
    const int t0=c<<5;
    if(t0>ws0+15) return;                   // causally dead wave (uniform branch)
    const float al0=ab[hb+t0+lm];
    const float al1=ab[hb+t0+16+lm];
#pragma unroll
    for(int tt=0;tt<2;tt++){
      f32x4 a0={0,0,0,0}, a1={0,0,0,0}, a2={0,0,0,0};
#pragma unroll
      for(int dc=0;dc<11;dc++){
        const bf16x8 kh=*reinterpret_cast<const bf16x8*>(&KV[buf][(tt*11+dc)*512+l*8]);
        const bf16x8 kl=*reinterpret_cast<const bf16x8*>(&KV[buf][(22+tt*11+dc)*512+l*8]);
        a0=__builtin_amdgcn_mfma_f32_16x16x32_bf16(qh[dc],kh,a0,0,0,0);
        a1=__builtin_amdgcn_mfma_f32_16x16x32_bf16(ql[dc],kh,a1,0,0,0);
        a2=__builtin_amdgcn_mfma_f32_16x16x32_bf16(qh[dc],kl,a2,0,0,0);
      }
      const float al=(tt==0)?al0:al1;
      const int tg=t0+tt*16+lm;
#pragma unroll
      for(int r=0;r<4;r++){
        const int srow=quad*4+r;
        const float qk=a0[r]+a1[r]+a2[r];
        const float e=fminf(al-Mr[r],0.f);
        const float msk=(tg<=ws0+srow)?1.f:0.f;
        Sc[w][srow][tt*16+lm]=(short)f2bf(msk*(qk*scale*expf(e)));
      }
    }
    const bf16x8 scf=*reinterpret_cast<const bf16x8*>(&Sc[w][lm][quad*8]);
#pragma unroll
    for(int nt=0;nt<22;nt++){
      const bf16x8 vf=*reinterpret_cast<const bf16x8*>(&KV[buf][(44+nt)*512+l*8]);
      accO[nt]=__builtin_amdgcn_mfma_f32_16x16x32_bf16(scf,vf,accO[nt],0,0,0);
    }
  };

  auto epilogue=[&](){
    const size_t pbase=(size_t)head*2048+ws0;
#pragma unroll
    for(int nt=0;nt<22;nt++){
      const int col=nt*16+lm;
#pragma unroll
      for(int r=0;r<4;r++){
        const int srow=quad*4+r;
        const float val=accO[nt][r];
        if(col<336){ if(val!=0.f) atomicAdd(&part[(pbase+srow)*336+col],val); }
        else if(col==336){ if(val!=0.f) atomicAdd(&rsum[pbase+srow],val); }
      }
    }
  };

  loadQ(ws0);
  stage(0,itemC(0));
  __syncthreads();                          // drains vmcnt: buffer 0 ready
  int cur=0;
  for(int i=0;i<nTot;i++){
    if(i+1<nTot) stage(cur^1,itemC(i+1));   // DMA next chunk into back buffer
    compute(itemC(i),cur);
    if(i==nA-1){                            // tile switch: A done
      epilogue();
      ws0=sbB*128+w*16;
      loadQ(ws0);
    }
    __syncthreads();                        // drain DMA + cross-wave sync
    cur^=1;
  }
  epilogue();                               // tile B
}

// ============================================================================
// finalize v3: normalizer + groupnorm + fused h_state, writing the down-GEMM
// A-FRAGMENTS (hi/lo bf16) directly (passing).
// ============================================================================
__global__ __launch_bounds__(256) void finalize3_k(const float* __restrict__ part,
                                                   const float* __restrict__ rsum,
                                                   const float* __restrict__ mtb,
                                                   const float* __restrict__ lnw,
                                                   const float* __restrict__ skip,
                                                   const float* __restrict__ act,
                                                   const float* __restrict__ xin,
                                                   unsigned short* __restrict__ hshi,
                                                   unsigned short* __restrict__ hslo){
  const int sblk=blockIdx.x, head=blockIdx.y;
  const int bI=head>>2, nh=head&3;
  const int s0=sblk*32;
  const int t=threadIdx.x, row=t>>3, sub=t&7;
  __shared__ float red1[32][8], red2[32][8];
  __shared__ float mu_s[32], rs_s[32], inv_s[32];
  const size_t pbase=(size_t)head*2048+s0;
  const float* prow=part+(pbase+row)*336;
  float s1=0.f,s2=0.f;
  for(int c=sub;c<336;c+=8){ const float v=prow[c]; s1+=v; s2+=v*v; }
  red1[row][sub]=s1; red2[row][sub]=s2;
  __syncthreads();
  if(sub==0){
    float a1=0.f,a2=0.f;
#pragma unroll
    for(int j=0;j<8;j++){ a1+=red1[row][j]; a2+=red2[row][j]; }
    const float mt=mtb[(size_t)head*S_+s0+row];
    const float nn=fmaxf(fabsf(rsum[pbase+row]), expf(fminf(fmaxf(-mt,-60.f),60.f)));
    const float inv=1.f/(nn+1e-6f);
    const float mu=a1*inv/336.f;
    const float var=a2*inv*inv/336.f-mu*mu;
    inv_s[row]=inv; mu_s[row]=mu;
    rs_s[row]=rsqrtf(fmaxf(var,0.f)+1e-5f);
  }
  __syncthreads();
  const float inv=inv_s[row], mu=mu_s[row], rs=rs_s[row];
  const size_t gbs=(size_t)(bI*S_+s0+row);       // global row in hs matrix
  const float* arow=act+gbs*H_+nh*DH_;
  const float* zrow=xin+gbs*H2_+H_+nh*DH_;
  const float* srw=skip+nh*DH_;
  const float* lrw=lnw+nh*DH_;
  const size_t mtbase=(gbs>>4)*42;
  const int lbase=(int)(gbs&15);
  for(int c=sub;c<336;c+=8){
    const float hn=(prow[c]*inv-mu)*rs*lrw[c];
    const float val=(hn+srw[c]*arow[c])*siluf(zrow[c]);
    const int h=nh*DH_+c;
    const int kc=h>>5, quad=(h>>3)&3, j=h&7;
    const size_t slot=(mtbase+kc)*64+lbase+16*quad;
    const unsigned short hi=f2bf(val);
    hshi[slot*8+j]=hi;
    hslo[slot*8+j]=f2bf(val-bf2f(hi));
  }
}

// ============================================================================
extern "C" void kernel_launch(void* const* d_in, const int* in_sizes, int n_in,
                              void* d_out, int out_size, void* d_ws, size_t ws_size,
                              hipStream_t stream){
  float* ws=(float*)d_ws;
  int* flag=(int*)ws;

  float* igb  = ws+O_IGB;
  float* logfb= ws+O_LOGF;
  float* ab   = ws+O_AB;
  float* Mbuf = ws+O_MB;
  float* mtb  = ws+O_MTB;
  float* f_ck = ws+O_CK;
  float* f_cb = ws+O_CB;
  float* f_wq = ws+O_WQ;
  float* f_wk = ws+O_WK;
  float* f_wv = ws+O_WV;
  float* f_wig= ws+O_WIG;
  float* f_big= ws+O_BIG;
  float* f_wfg= ws+O_WFG;
  float* f_bfg= ws+O_BFG;
  float* f_lnw= ws+O_LNW;
  float* f_skp= ws+O_SKP;
  float* xin  = ws+O_XIN;
  float* act  = ws+O_ACT;
  float* qb   = ws+O_QB;
  float* kb   = ws+O_KB;
  float* vb   = ws+O_VB;

  unsigned short* xhi  =(unsigned short*)(ws+O_FX);   unsigned short* xlo  =xhi+N_X;
  unsigned short* wuphi=(unsigned short*)(ws+O_FWUP); unsigned short* wuplo=wuphi+N_WUP;
  unsigned short* wdnhi=(unsigned short*)(ws+O_FWDN); unsigned short* wdnlo=wdnhi+N_WDN;
  unsigned short* khi=(unsigned short*)(ws+O_FX);     // x/wup frags dead after up-gemm
  unsigned short* klo=khi+KSPLIT_SHORTS;
  unsigned short* vTf=(unsigned short*)(ws+O_HOUT);   // hout region: fully dead
  unsigned short* hshi=(unsigned short*)kb;    // kb region unused (K goes direct)
  unsigned short* hslo=hshi+N_BSH;
  float* partb=vb;                             // vb dead after vwprep (zeroed there)
  float* rsumb=igb;                            // igb dead after scan fold (zeroed there)

  detect_k<<<1,256,0,stream>>>((const unsigned short*)d_in[0],flag);
  // merged prep: x A-frags + Wup B-frags + 11 small weight conversions
  prepAB_k<<<2048+1344+226,256,0,stream>>>(d_in[0],d_in[1],flag,xhi,xlo,wuphi,wuplo,
                                           d_in[2],d_in[3],d_in[4],d_in[5],d_in[6],
                                           d_in[7],d_in[8],d_in[9],d_in[10],d_in[11],
                                           d_in[12],ws);
  // up-GEMM: xin = x @ Wup  (M=4096,K=1024 kcn=32, N=2688)
  gemm3_k<<<dim3(2688/128,4096/128),256,0,stream>>>(xhi,xlo,wuphi,wuplo,xin,nullptr,32,H2_);

  // fused conv+SiLU+qkv+gates + direct K-frag emit
  convqkvgates_k<<<BS_,384,0,stream>>>(xin,f_ck,f_cb,f_wq,f_wk,f_wv,
                                       f_wig,f_big,f_wfg,f_bfg,
                                       act,qb,vb,khi,klo,igb,logfb);
  // V frags + part-zero + Wdn frags + K-pad zero + scan (all independent)
  vwprep_k<<<512+672+64+8,256,0,stream>>>(vb,d_in[13],flag,vTf,wdnhi,wdnlo,
                                          khi,klo,partb,
                                          igb,logfb,ab,Mbuf,mtb);
  // mLSTM v12 (proven): 256 blocks x 512 thr
  mlstm6_k<<<256,512,0,stream>>>(qb,khi,klo,vTf,ab,Mbuf,partb,rsumb);
  // finalize v3: groupnorm + h_state + DIRECT A-frag emit
  finalize3_k<<<dim3(S_/32,B_*NH_),256,0,stream>>>(partb,rsumb,mtb,f_lnw,f_skp,act,xin,
                                                   hshi,hslo);
  // down-GEMM: 128x64 tile -> 512 blocks (full machine), direct to d_out
  gemm4_k<<<dim3(1024/64,4096/128),256,0,stream>>>(hshi,hslo,wdnhi,wdnlo,d_out,flag,42,E_);
}

// Round 16
// 428.838 us; speedup vs baseline: 1.0296x; 1.0296x over previous
//
#include <hip/hip_runtime.h>
#include <cmath>

#define DI __device__ __forceinline__

constexpr int B_=2, S_=2048, E_=1024, H_=1344, NH_=4, DH_=336;
constexpr int BS_=B_*S_, H2_=2*H_;
constexpr int NG_=B_*NH_*S_;   // 16384

constexpr size_t N_X=(size_t)BS_*E_;
constexpr size_t N_WUP=(size_t)E_*H2_;
constexpr size_t N_WDN=(size_t)H_*E_;
constexpr size_t N_BSH=(size_t)BS_*H_;
constexpr size_t N_BSH2=(size_t)BS_*H2_;
constexpr size_t N_WH=5376, N_WG=16128, N_CK=4*H_;

// ---- ws layout (floats); identical to prior passing rounds ----
constexpr size_t O_IGB = 64;
constexpr size_t O_LOGF= O_IGB + NG_;
constexpr size_t O_AB  = O_LOGF+ NG_;
constexpr size_t O_MB  = O_AB  + NG_;
constexpr size_t O_MTB = O_MB  + NG_;
constexpr size_t O_CK  = O_MTB + NG_;
constexpr size_t O_CB  = O_CK  + N_CK;
constexpr size_t O_WQ  = O_CB  + H_;
constexpr size_t O_WK  = O_WQ  + N_WH;
constexpr size_t O_WV  = O_WK  + N_WH;
constexpr size_t O_WIG = O_WV  + N_WH;
constexpr size_t O_BIG = O_WIG + N_WG;
constexpr size_t O_WFG = O_BIG + 16;
constexpr size_t O_BFG = O_WFG + N_WG;
constexpr size_t O_LNW = O_BFG + 16;
constexpr size_t O_SKP = O_LNW + H_;
constexpr size_t O_FX  = O_SKP + H_;
constexpr size_t O_FWUP= O_FX  + N_X;
constexpr size_t O_FWDN= O_FWUP+ N_WUP;
constexpr size_t O_XIN = O_FWDN+ N_WDN;
constexpr size_t O_ACT = O_XIN + N_BSH2;
constexpr size_t O_QB  = O_ACT + N_BSH;
constexpr size_t O_KB  = O_QB  + N_BSH;
constexpr size_t O_VB  = O_KB  + N_BSH;
constexpr size_t O_HOUT= O_VB  + N_BSH;

// khi/klo: [head][tile=t/16][dc=0..10][l][8] bf16 (B-frag 16x16x32)
constexpr size_t KSPLIT_SHORTS=(size_t)8*128*11*64*8;  // 5,767,168
// vTf: [head][tc=t/32][ntg=0..21][l][8] bf16; n==336 -> 1.0 (rowsum), n>336 -> 0
constexpr size_t VT_SHORTS=(size_t)8*64*22*64*8;       // 5,767,168

typedef __attribute__((ext_vector_type(8))) short bf16x8;
typedef __attribute__((ext_vector_type(4))) float f32x4;

DI float bf2f(unsigned int u){union{unsigned int i;float f;}v;v.i=(u&0xffffu)<<16;return v.f;}
DI unsigned short f2bf(float f){union{float f;unsigned int i;}v;v.f=f;unsigned int x=v.i;
  return (unsigned short)((x+0x7fffu+((x>>16)&1u))>>16);}
DI float siluf(float x){return x/(1.f+expf(-x));}
DI float logsigf(float x){return (x>=0.f)?-log1pf(expf(-x)):x-log1pf(expf(x));}
DI void load4(const float* p, float* d){float4 v=*reinterpret_cast<const float4*>(p);
  d[0]=v.x;d[1]=v.y;d[2]=v.z;d[3]=v.w;}

// ---- dtype detect (fp32 proven; keep the guard) ----
__global__ __launch_bounds__(256) void detect_k(const unsigned short* __restrict__ xraw,
                                                int* __restrict__ flag){
  __shared__ int cnt_s;
  if(threadIdx.x==0) cnt_s=0;
  __syncthreads();
  int c=0;
  for(int i=threadIdx.x;i<2048;i+=256){
    const unsigned e=(xraw[i]>>7)&0xFFu;
    if(e>=0x90u) c++;
  }
  atomicAdd(&cnt_s,c);
  __syncthreads();
  if(threadIdx.x==0) *flag=(cnt_s>16)?0:1;
}

constexpr int CV0=5376, CV1=CV0+1344, CV2=CV1+5376, CV3=CV2+5376, CV4=CV3+5376,
              CV5=CV4+16128, CV6=CV5+4, CV7=CV6+16128, CV8=CV7+4,
              CV9=CV8+1344, CVT=CV9+1344;     // 57800 total

// ============================================================================
// MERGED prep: blk<2048 -> x A-frags; blk<3392 -> Wup B-frags; else convall
// tail (11 small weight tensors -> ws fp32). All read *flag.
// ============================================================================
__global__ __launch_bounds__(256) void prepAB_k(const void* __restrict__ xsrc,
    const void* __restrict__ wsrc, const int* __restrict__ flag,
    unsigned short* __restrict__ xhi, unsigned short* __restrict__ xlo,
    unsigned short* __restrict__ whi, unsigned short* __restrict__ wlo,
    const void* s2,const void* s3,const void* s4,const void* s5,const void* s6,
    const void* s7,const void* s8,const void* s9,const void* s10,const void* s11,
    const void* s12, float* __restrict__ ws){
  const int blk=blockIdx.x;
  const int fl=*flag;
  if(blk>=3392){
    const int i=(blk-3392)*256+threadIdx.x;
    if(i>=CVT) return;
    const void* src; int off; size_t dst;
    if(i<CV0){src=s2; off=i;      dst=O_CK +off;}
    else if(i<CV1){src=s3; off=i-CV0; dst=O_CB +off;}
    else if(i<CV2){src=s4; off=i-CV1; dst=O_WQ +off;}
    else if(i<CV3){src=s5; off=i-CV2; dst=O_WK +off;}
    else if(i<CV4){src=s6; off=i-CV3; dst=O_WV +off;}
    else if(i<CV5){src=s7; off=i-CV4; dst=O_WIG+off;}
    else if(i<CV6){src=s8; off=i-CV5; dst=O_BIG+off;}
    else if(i<CV7){src=s9; off=i-CV6; dst=O_WFG+off;}
    else if(i<CV8){src=s10;off=i-CV7; dst=O_BFG+off;}
    else if(i<CV9){src=s11;off=i-CV8; dst=O_LNW+off;}
    else          {src=s12;off=i-CV9; dst=O_SKP+off;}
    ws[dst]=fl?bf2f(((const unsigned short*)src)[off])
              :((const float*)src)[off];
    return;
  }
  float v[8];
  unsigned short* dh; unsigned short* dl; size_t slot;
  if(blk<2048){
    slot=(size_t)blk*256+threadIdx.x;       // exactly 524288 = 256*32*64
    const int l=(int)slot&63, rest=(int)(slot>>6);
    const int kc=rest&31, mt=rest>>5;
    const int row=mt*16+(l&15), k0=kc*32+(l>>4)*8;
    if(fl){
      const unsigned short* s=(const unsigned short*)xsrc+(size_t)row*1024+k0;
      const uint4 u=*reinterpret_cast<const uint4*>(s);
      v[0]=bf2f(u.x);v[1]=bf2f(u.x>>16);v[2]=bf2f(u.y);v[3]=bf2f(u.y>>16);
      v[4]=bf2f(u.z);v[5]=bf2f(u.z>>16);v[6]=bf2f(u.w);v[7]=bf2f(u.w>>16);
    }else{
      const float* s=(const float*)xsrc+(size_t)row*1024+k0;
      load4(s,v); load4(s+4,v+4);
    }
    dh=xhi; dl=xlo;
  } else {
    slot=(size_t)(blk-2048)*256+threadIdx.x; // exactly 344064 = 168*32*64
    const int l=(int)slot&63, rest=(int)(slot>>6);
    const int kc=rest&31, nt=rest>>5;
    const int col=nt*16+(l&15), row0=kc*32+(l>>4)*8;
    if(fl){
      const unsigned short* s=(const unsigned short*)wsrc;
#pragma unroll
      for(int j=0;j<8;j++) v[j]=bf2f(s[(size_t)(row0+j)*2688+col]);
    }else{
      const float* s=(const float*)wsrc;
#pragma unroll
      for(int j=0;j<8;j++) v[j]=s[(size_t)(row0+j)*2688+col];
    }
    dh=whi; dl=wlo;
  }
  unsigned short h8[8], l8[8];
#pragma unroll
  for(int j=0;j<8;j++){ h8[j]=f2bf(v[j]); l8[j]=f2bf(v[j]-bf2f(h8[j])); }
  uint4 ph,pl;
  ph.x=(unsigned)h8[0]|((unsigned)h8[1]<<16); ph.y=(unsigned)h8[2]|((unsigned)h8[3]<<16);
  ph.z=(unsigned)h8[4]|((unsigned)h8[5]<<16); ph.w=(unsigned)h8[6]|((unsigned)h8[7]<<16);
  pl.x=(unsigned)l8[0]|((unsigned)l8[1]<<16); pl.y=(unsigned)l8[2]|((unsigned)l8[3]<<16);
  pl.z=(unsigned)l8[4]|((unsigned)l8[5]<<16); pl.w=(unsigned)l8[6]|((unsigned)l8[7]<<16);
  *reinterpret_cast<uint4*>(&dh[slot*8])=ph;
  *reinterpret_cast<uint4*>(&dl[slot*8])=pl;
}

// ============================================================================
// GEMM v3: 128x128 tile, 4 waves, counted-vmcnt pipeline (passing).
// Used for BOTH GEMMs (round-15's 128x64 down-GEMM variant regressed:
// arithmetic intensity per staged byte 6 -> 4 MFMA/tile and A-fetch x2
// outweighed the occupancy gain).
// ============================================================================
__global__ __launch_bounds__(256) void gemm3_k(
    const unsigned short* __restrict__ Ahi, const unsigned short* __restrict__ Alo,
    const unsigned short* __restrict__ Bhi, const unsigned short* __restrict__ Blo,
    void* __restrict__ C, const int* __restrict__ flag, int kcn, int ldc){
  const int t=threadIdx.x, w=t>>6, l=t&63, lm=l&15, quad=l>>4;
  const int bn=blockIdx.x*128, bm=blockIdx.y*128;
  const int mtg0=bm>>4, ntg0=bn>>4;

  __shared__ short TT[2][32*512];           // [0-7]Ahi [8-15]Alo [16-23]Bhi [24-31]Blo

  f32x4 acc[2][8];
#pragma unroll
  for(int g=0;g<2;g++)
#pragma unroll
    for(int nt=0;nt<8;nt++) acc[g][nt]={0.f,0.f,0.f,0.f};

  auto stage=[&](int buf,int kc){
#pragma unroll
    for(int j=0;j<8;j++){
      const int tr=w*8+j;
      const unsigned short* src;
      if(tr<8)       src=&Ahi[((size_t)(mtg0+tr   )*kcn+kc)*512+(size_t)l*8];
      else if(tr<16) src=&Alo[((size_t)(mtg0+tr-8 )*kcn+kc)*512+(size_t)l*8];
      else if(tr<24) src=&Bhi[((size_t)(ntg0+tr-16)*kcn+kc)*512+(size_t)l*8];
      else           src=&Blo[((size_t)(ntg0+tr-24)*kcn+kc)*512+(size_t)l*8];
      __builtin_amdgcn_global_load_lds(
        (const __attribute__((address_space(1))) unsigned int*)src,
        (__attribute__((address_space(3))) unsigned int*)&TT[buf][tr*512],
        16,0,0);
    }
  };

  auto compute=[&](int buf){
    const short* Tb=&TT[buf][0];
    const bf16x8 ah0=*reinterpret_cast<const bf16x8*>(&Tb[(2*w  )*512+l*8]);
    const bf16x8 ah1=*reinterpret_cast<const bf16x8*>(&Tb[(2*w+1)*512+l*8]);
    const bf16x8 al0=*reinterpret_cast<const bf16x8*>(&Tb[(8+2*w  )*512+l*8]);
    const bf16x8 al1=*reinterpret_cast<const bf16x8*>(&Tb[(8+2*w+1)*512+l*8]);
#pragma unroll
    for(int nt=0;nt<8;nt++){
      const bf16x8 bh=*reinterpret_cast<const bf16x8*>(&Tb[(16+nt)*512+l*8]);
      const bf16x8 bl=*reinterpret_cast<const bf16x8*>(&Tb[(24+nt)*512+l*8]);
      acc[0][nt]=__builtin_amdgcn_mfma_f32_16x16x32_bf16(ah0,bh,acc[0][nt],0,0,0);
      acc[0][nt]=__builtin_amdgcn_mfma_f32_16x16x32_bf16(al0,bh,acc[0][nt],0,0,0);
      acc[0][nt]=__builtin_amdgcn_mfma_f32_16x16x32_bf16(ah0,bl,acc[0][nt],0,0,0);
      acc[1][nt]=__builtin_amdgcn_mfma_f32_16x16x32_bf16(ah1,bh,acc[1][nt],0,0,0);
      acc[1][nt]=__builtin_amdgcn_mfma_f32_16x16x32_bf16(al1,bh,acc[1][nt],0,0,0);
      acc[1][nt]=__builtin_amdgcn_mfma_f32_16x16x32_bf16(ah1,bl,acc[1][nt],0,0,0);
    }
  };

  stage(0,0);
  for(int kc=0;kc<kcn;kc++){
    const int cur=kc&1;
    if(kc+1<kcn){
      stage(cur^1,kc+1);                    // prefetch stays in flight
      asm volatile("s_waitcnt vmcnt(8)" ::: "memory");   // wait prev 8 only
    } else {
      asm volatile("s_waitcnt vmcnt(0)" ::: "memory");
    }
    __builtin_amdgcn_s_barrier();           // all waves' cur-step loads landed
    compute(cur);
    __builtin_amdgcn_s_barrier();           // protect buffer overwrite
  }

  const int bf=flag?*flag:0;
#pragma unroll
  for(int g=0;g<2;g++)
#pragma unroll
    for(int nt=0;nt<8;nt++)
#pragma unroll
      for(int r=0;r<4;r++){
        const size_t idx=(size_t)(bm+(2*w+g)*16+quad*4+r)*ldc+bn+nt*16+lm;
        if(bf) ((unsigned short*)C)[idx]=f2bf(acc[g][nt][r]);
        else   ((float*)C)[idx]=acc[g][nt][r];
      }
}

// ============================================================================
// FUSED conv_act + qkv + gates + DIRECT K-frag emit (passing, round 14).
// ============================================================================
__global__ __launch_bounds__(384) void convqkvgates_k(
    const float* __restrict__ xin, const float* __restrict__ ck,
    const float* __restrict__ cb,
    const float* __restrict__ Wq, const float* __restrict__ Wk,
    const float* __restrict__ Wv,
    const float* __restrict__ Wig, const float* __restrict__ big,
    const float* __restrict__ Wfg, const float* __restrict__ bfg,
    float* __restrict__ act, float* __restrict__ qb, float* __restrict__ vb,
    unsigned short* __restrict__ khi, unsigned short* __restrict__ klo,
    float* __restrict__ igb, float* __restrict__ logfb){
  const int bs=blockIdx.x;
  const int b=bs>>11, s=bs&2047;
  const int t=threadIdx.x;
  __shared__ float4 sq4[336], sk4[336], sv4[336];
  __shared__ float red[6][8];
  if(t<336){
    const int ph=t, base=ph*4;
    float xc[4];
#pragma unroll
    for(int d=0;d<4;d++) xc[d]=cb[base+d];
    float xm[4]={0.f,0.f,0.f,0.f};
#pragma unroll
    for(int w=0;w<4;w++){
      const int sr=s-3+w;
      if(sr>=0){
        float xv[4];
        load4(&xin[(size_t)(b*S_+sr)*H2_+base],xv);
#pragma unroll
        for(int d=0;d<4;d++) xc[d]+=xv[d]*ck[w*H_+base+d];
        if(w==3){ xm[0]=xv[0];xm[1]=xv[1];xm[2]=xv[2];xm[3]=xv[3]; }
      }
    }
    float a4[4];
#pragma unroll
    for(int d=0;d<4;d++) a4[d]=siluf(xc[d]);
    *reinterpret_cast<float4*>(&act[(size_t)bs*H_+base])
        =make_float4(a4[0],a4[1],a4[2],a4[3]);
    float q4[4],k4[4],v4[4];
#pragma unroll
    for(int o=0;o<4;o++){
      float q=0.f,k=0.f,v=0.f;
#pragma unroll
      for(int d=0;d<4;d++){
        q+=a4[d]*Wq[ph*16+d*4+o];
        k+=a4[d]*Wk[ph*16+d*4+o];
        v+=xm[d]*Wv[ph*16+d*4+o];
      }
      q4[o]=q;k4[o]=k;v4[o]=v;
    }
    const int nh=ph/84, dh0=(ph-nh*84)*4;   // 4 outputs stay in one head
    const size_t off=((size_t)(b*NH_+nh)*S_+s)*DH_+dh0;
    *reinterpret_cast<float4*>(&qb[off])=make_float4(q4[0],q4[1],q4[2],q4[3]);
    *reinterpret_cast<float4*>(&vb[off])=make_float4(v4[0],v4[1],v4[2],v4[3]);
    // direct K-frag emit (hi/lo), replacing the kb round-trip
    {
      const int head8=b*NH_+nh;
      const int tt=s>>4, lm=s&15;
      const int dc=dh0>>5, quad=(dh0&31)>>3, j=dh0&7;  // j in {0,4}
      const size_t ob=(((size_t)(head8*128+tt)*11)+dc)*512
                      +(size_t)(quad*16+lm)*8+j;
      unsigned short kh[4], kl[4];
#pragma unroll
      for(int o=0;o<4;o++){
        kh[o]=f2bf(k4[o]);
        kl[o]=f2bf(k4[o]-bf2f(kh[o]));
      }
      uint2 pk, pl;
      pk.x=(unsigned)kh[0]|((unsigned)kh[1]<<16);
      pk.y=(unsigned)kh[2]|((unsigned)kh[3]<<16);
      pl.x=(unsigned)kl[0]|((unsigned)kl[1]<<16);
      pl.y=(unsigned)kl[2]|((unsigned)kl[3]<<16);
      *reinterpret_cast<uint2*>(&khi[ob])=pk;
      *reinterpret_cast<uint2*>(&klo[ob])=pl;
    }
    sq4[ph]=make_float4(q4[0],q4[1],q4[2],q4[3]);
    sk4[ph]=make_float4(k4[0],k4[1],k4[2],k4[3]);
    sv4[ph]=make_float4(v4[0],v4[1],v4[2],v4[3]);
  }
  __syncthreads();
  const float* sq=reinterpret_cast<const float*>(sq4);
  const float* sk=reinterpret_cast<const float*>(sk4);
  const float* sv=reinterpret_cast<const float*>(sv4);
  float aI0=0.f,aI1=0.f,aI2=0.f,aI3=0.f;
  float aF0=0.f,aF1=0.f,aF2=0.f,aF3=0.f;
  for(int h=t; h<H_; h+=384){
    const float q=sq[h], k=sk[h], v=sv[h];
    const float4 wiq=*reinterpret_cast<const float4*>(&Wig[(size_t)h*4]);
    const float4 wik=*reinterpret_cast<const float4*>(&Wig[(size_t)(H_+h)*4]);
    const float4 wiv=*reinterpret_cast<const float4*>(&Wig[(size_t)(2*H_+h)*4]);
    const float4 wfq=*reinterpret_cast<const float4*>(&Wfg[(size_t)h*4]);
    const float4 wfk=*reinterpret_cast<const float4*>(&Wfg[(size_t)(H_+h)*4]);
    const float4 wfv=*reinterpret_cast<const float4*>(&Wfg[(size_t)(2*H_+h)*4]);
    aI0+=q*wiq.x+k*wik.x+v*wiv.x;
    aI1+=q*wiq.y+k*wik.y+v*wiv.y;
    aI2+=q*wiq.z+k*wik.z+v*wiv.z;
    aI3+=q*wiq.w+k*wik.w+v*wiv.w;
    aF0+=q*wfq.x+k*wfk.x+v*wfv.x;
    aF1+=q*wfq.y+k*wfk.y+v*wfv.y;
    aF2+=q*wfq.z+k*wfk.z+v*wfv.z;
    aF3+=q*wfq.w+k*wfk.w+v*wfv.w;
  }
#pragma unroll
  for(int m=1;m<64;m<<=1){
    aI0+=__shfl_xor(aI0,m); aI1+=__shfl_xor(aI1,m);
    aI2+=__shfl_xor(aI2,m); aI3+=__shfl_xor(aI3,m);
    aF0+=__shfl_xor(aF0,m); aF1+=__shfl_xor(aF1,m);
    aF2+=__shfl_xor(aF2,m); aF3+=__shfl_xor(aF3,m);
  }
  const int wv=t>>6, l=t&63;
  if(l==0){
    red[wv][0]=aI0; red[wv][1]=aI1; red[wv][2]=aI2; red[wv][3]=aI3;
    red[wv][4]=aF0; red[wv][5]=aF1; red[wv][6]=aF2; red[wv][7]=aF3;
  }
  __syncthreads();
  if(t==0){
    float r[8];
#pragma unroll
    for(int j=0;j<8;j++){
      float a=0.f;
#pragma unroll
      for(int wv2=0;wv2<6;wv2++) a+=red[wv2][j];
      r[j]=a;
    }
#pragma unroll
    for(int n=0;n<4;n++){
      const size_t o=(size_t)(b*NH_+n)*S_+s;
      igb[o]=r[n]+big[n];
      logfb[o]=logsigf(r[4+n]+bfg[n]);
    }
  }
}

// ============================================================================
// MERGED V/Wdn prep + K-pad zero + SCAN (passing, round 15).
// ============================================================================
__global__ __launch_bounds__(256) void vwprep_k(const float* vb,
                                                const void* __restrict__ wdnsrc,
                                                const int* __restrict__ flag,
                                                unsigned short* __restrict__ vTf,
                                                unsigned short* __restrict__ wdnhi,
                                                unsigned short* __restrict__ wdnlo,
                                                unsigned short* __restrict__ khi,
                                                unsigned short* __restrict__ klo,
                                                float* partz,
                                                float* igm,
                                                const float* __restrict__ logfb,
                                                float* __restrict__ ab,
                                                float* __restrict__ Mb,
                                                float* __restrict__ mtb){
  const int blk=blockIdx.x;
  if(blk<512){
    const int head=blk>>6, tc=blk&63;
    const size_t obase=(size_t)blk*22*512;
    for(int slot=threadIdx.x; slot<1408; slot+=256){
      const int ntg=slot>>6, ll=slot&63, quad=ll>>4, lm=ll&15;
      const int n=ntg*16+lm, t0=tc*32+quad*8;
      unsigned short h8[8];
#pragma unroll
      for(int j=0;j<8;j++){
        float val;
        if(n<336)       val=vb[((size_t)head*S_+t0+j)*DH_+n];
        else if(n==336) val=1.f;
        else            val=0.f;
        h8[j]=f2bf(val);
      }
      uint4 pk;
      pk.x=(unsigned)h8[0]|((unsigned)h8[1]<<16); pk.y=(unsigned)h8[2]|((unsigned)h8[3]<<16);
      pk.z=(unsigned)h8[4]|((unsigned)h8[5]<<16); pk.w=(unsigned)h8[6]|((unsigned)h8[7]<<16);
      *reinterpret_cast<uint4*>(&vTf[obase+(size_t)(ntg*64+ll)*8])=pk;
    }
    __syncthreads();                        // all reads of this slab done
    const size_t zb=((size_t)head*2048+(size_t)tc*32)*336;
    for(int idx=threadIdx.x; idx<32*336; idx+=256) partz[zb+idx]=0.f;
  } else if(blk<1184){
    const size_t slot=(size_t)(blk-512)*256+threadIdx.x;  // exact 172032
    const int l=(int)slot&63, rest=(int)(slot>>6);
    const int kc=rest%42, nt=rest/42;
    const int col=nt*16+(l&15), row0=kc*32+(l>>4)*8;
    const int fl=*flag;
    float v[8];
    if(fl){
      const unsigned short* s=(const unsigned short*)wdnsrc;
#pragma unroll
      for(int j=0;j<8;j++) v[j]=bf2f(s[(size_t)(row0+j)*1024+col]);
    }else{
      const float* s=(const float*)wdnsrc;
#pragma unroll
      for(int j=0;j<8;j++) v[j]=s[(size_t)(row0+j)*1024+col];
    }
    unsigned short h8[8], l8[8];
#pragma unroll
    for(int j=0;j<8;j++){ h8[j]=f2bf(v[j]); l8[j]=f2bf(v[j]-bf2f(h8[j])); }
    uint4 ph,pl;
    ph.x=(unsigned)h8[0]|((unsigned)h8[1]<<16); ph.y=(unsigned)h8[2]|((unsigned)h8[3]<<16);
    ph.z=(unsigned)h8[4]|((unsigned)h8[5]<<16); ph.w=(unsigned)h8[6]|((unsigned)h8[7]<<16);
    pl.x=(unsigned)l8[0]|((unsigned)l8[1]<<16); pl.y=(unsigned)l8[2]|((unsigned)l8[3]<<16);
    pl.z=(unsigned)l8[4]|((unsigned)l8[5]<<16); pl.w=(unsigned)l8[6]|((unsigned)l8[7]<<16);
    *reinterpret_cast<uint4*>(&wdnhi[slot*8])=ph;
    *reinterpret_cast<uint4*>(&wdnlo[slot*8])=pl;
  } else if(blk<1248){
    // K-pad zero: 1024 k-tiles, shorts [256,512) of the dc=10 sub-tile.
    const int idx=(blk-1184)*256+threadIdx.x;   // 0..16383
    const int kt=idx>>4, u=idx&15;
    const size_t base_s=(((size_t)kt*11)+10)*512 + 256 + (size_t)u*16;
    const uint4 z={0,0,0,0};
    *reinterpret_cast<uint4*>(&khi[base_s])=z;
    *reinterpret_cast<uint4*>(&klo[base_s])=z;
  } else {
    // per-head scan + rsum-zero fold (8 blocks)
    const int head=blk-1248, t=threadIdx.x;
    __shared__ float sh[256];
    const float* lf=logfb+(size_t)head*S_;
    float* ig=igm+(size_t)head*S_;
    float lc[8];
    float run=0.f;
#pragma unroll
    for(int i=0;i<8;i++){ run+=lf[t*8+i]; lc[i]=run; }
    sh[t]=run;
    for(int st=1;st<256;st<<=1){
      __syncthreads();
      const float v=(t>=st)?sh[t-st]:0.f;
      __syncthreads();
      sh[t]+=v;
    }
    __syncthreads();
    const float off=(t==0)?0.f:sh[t-1];
    __syncthreads();
    float av[8],mv[8],cv[8];
    float mrun=-1e30f;
#pragma unroll
    for(int i=0;i<8;i++){
      cv[i]=off+lc[i];
      av[i]=ig[t*8+i]-cv[i];
      mrun=fmaxf(mrun,av[i]);
      mv[i]=mrun;
    }
    sh[t]=mrun;
    for(int st=1;st<256;st<<=1){
      __syncthreads();
      const float v=(t>=st)?sh[t-st]:-1e30f;
      __syncthreads();
      sh[t]=fmaxf(sh[t],v);
    }
    __syncthreads();
    const float moff=(t==0)?-1e30f:sh[t-1];
#pragma unroll
    for(int i=0;i<8;i++){
      const float Mi=fmaxf(moff,mv[i]);
      const size_t j=(size_t)head*S_+t*8+i;
      ab[j]=av[i]; Mb[j]=Mi; mtb[j]=cv[i]+Mi;
      ig[t*8+i]=0.f;                        // rsum zero (same buffer, after read)
    }
  }
}

// ============================================================================
// mLSTM v12 (proven 113 µs) — 512 threads: 8 waves x 16 rows = 128-row
// supertiles, paired p<->15-p, 4-way seg: 256 blocks x 17 chunks.
// ============================================================================
__global__ __launch_bounds__(512,1) void mlstm6_k(
    const float* __restrict__ qb, const unsigned short* __restrict__ khi,
    const unsigned short* __restrict__ klo, const unsigned short* __restrict__ vTf,
    const float* __restrict__ ab, const float* __restrict__ Mb,
    float* __restrict__ part, float* __restrict__ rsum){
  const int bid=blockIdx.x;
  const int head=bid&7;                     // XCD pin: head h -> XCD h
  const int rest=bid>>3;                    // 0..31
  const int pairI=rest&7, seg=rest>>3;      // pair 0..7, seg 0..3
  const int t=threadIdx.x, w=t>>6, l=t&63, lm=l&15, quad=l>>4;

  __shared__ short KV[2][66*512];
  __shared__ short Sc[8][16][40];

  const size_t hb=(size_t)head*S_;
  const float scale=0.05455447256f;         // 336^-0.5

  const int sbA=pairI, sbB=15-pairI;        // 128-row supertiles
  const int nA=pairI+1, nTot=17;            // uniform work across all blocks

  bf16x8 qh[11], ql[11];
  f32x4 accO[22];
  float Mr[4];
  int ws0=sbA*128+w*16;

  auto loadQ=[&](int ws0_){
    const float* qrow=qb+(hb+ws0_+lm)*DH_;
#pragma unroll
    for(int dc=0;dc<11;dc++){
      const int dbase=dc*32+quad*8;
      float v[8];
      if(dbase<336){ load4(qrow+dbase,v); load4(qrow+dbase+4,v+4); }
      else { for(int j=0;j<8;j++) v[j]=0.f; }
#pragma unroll
      for(int j=0;j<8;j++){
        const unsigned short h=f2bf(v[j]);
        qh[dc][j]=(short)h;
        ql[dc][j]=(short)f2bf(v[j]-bf2f(h));
      }
    }
#pragma unroll
    for(int r=0;r<4;r++) Mr[r]=Mb[hb+ws0_+quad*4+r];
#pragma unroll
    for(int n=0;n<22;n++) accO[n]={0.f,0.f,0.f,0.f};
  };

  auto itemC=[&](int i)->int{
    return (i<nA)? (seg+4*i) : (seg+4*(i-nA));
  };

  auto stage=[&](int buf,int c){
    const size_t kbase=(((size_t)head*128+(size_t)(2*c))*11)*512+(size_t)l*8;
    const size_t vbase=(((size_t)head*64+(size_t)c)*22)*512+(size_t)l*8;
#pragma unroll
    for(int j=0;j<9;j++){
      const int tr=w+8*j;
      if(tr<66){
        const unsigned short* src;
        if(tr<22)      src=&khi[kbase+(size_t)tr*512];
        else if(tr<44) src=&klo[kbase+(size_t)(tr-22)*512];
        else           src=&vTf[vbase+(size_t)(tr-44)*512];
        __builtin_amdgcn_global_load_lds(
          (const __attribute__((address_space(1))) unsigned int*)src,
          (__attribute__((address_space(3))) unsigned int*)&KV[buf][(size_t)tr*512],
          16,0,0);
      }
    }
  };

  auto compute=[&](int c,int buf){
    const int t0=c<<5;
    if(t0>ws0+15) return;                   // causally dead wave (uniform branch)
    const float al0=ab[hb+t0+lm];
    const float al1=ab[hb+t0+16+lm];
#pragma unroll
    for(int tt=0;tt<2;tt++){
      f32x4 a0={0,0,0,0}, a1={0,0,0,0}, a2={0,0,0,0};
#pragma unroll
      for(int dc=0;dc<11;dc++){
        const bf16x8 kh=*reinterpret_cast<const bf16x8*>(&KV[buf][(tt*11+dc)*512+l*8]);
        const bf16x8 kl=*reinterpret_cast<const bf16x8*>(&KV[buf][(22+tt*11+dc)*512+l*8]);
        a0=__builtin_amdgcn_mfma_f32_16x16x32_bf16(qh[dc],kh,a0,0,0,0);
        a1=__builtin_amdgcn_mfma_f32_16x16x32_bf16(ql[dc],kh,a1,0,0,0);
        a2=__builtin_amdgcn_mfma_f32_16x16x32_bf16(qh[dc],kl,a2,0,0,0);
      }
      const float al=(tt==0)?al0:al1;
      const int tg=t0+tt*16+lm;
#pragma unroll
      for(int r=0;r<4;r++){
        const int srow=quad*4+r;
        const float qk=a0[r]+a1[r]+a2[r];
        const float e=fminf(al-Mr[r],0.f);
        const float msk=(tg<=ws0+srow)?1.f:0.f;
        Sc[w][srow][tt*16+lm]=(short)f2bf(msk*(qk*scale*expf(e)));
      }
    }
    const bf16x8 scf=*reinterpret_cast<const bf16x8*>(&Sc[w][lm][quad*8]);
#pragma unroll
    for(int nt=0;nt<22;nt++){
      const bf16x8 vf=*reinterpret_cast<const bf16x8*>(&KV[buf][(44+nt)*512+l*8]);
      accO[nt]=__builtin_amdgcn_mfma_f32_16x16x32_bf16(scf,vf,accO[nt],0,0,0);
    }
  };

  auto epilogue=[&](){
    const size_t pbase=(size_t)head*2048+ws0;
#pragma unroll
    for(int nt=0;nt<22;nt++){
      const int col=nt*16+lm;
#pragma unroll
      for(int r=0;r<4;r++){
        const int srow=quad*4+r;
        const float val=accO[nt][r];
        if(col<336){ if(val!=0.f) atomicAdd(&part[(pbase+srow)*336+col],val); }
        else if(col==336){ if(val!=0.f) atomicAdd(&rsum[pbase+srow],val); }
      }
    }
  };

  loadQ(ws0);
  stage(0,itemC(0));
  __syncthreads();                          // drains vmcnt: buffer 0 ready
  int cur=0;
  for(int i=0;i<nTot;i++){
    if(i+1<nTot) stage(cur^1,itemC(i+1));   // DMA next chunk into back buffer
    compute(itemC(i),cur);
    if(i==nA-1){                            // tile switch: A done
      epilogue();
      ws0=sbB*128+w*16;
      loadQ(ws0);
    }
    __syncthreads();                        // drain DMA + cross-wave sync
    cur^=1;
  }
  epilogue();                               // tile B
}

// ============================================================================
// finalize v3: normalizer + groupnorm + fused h_state, writing the down-GEMM
// A-FRAGMENTS (hi/lo bf16) directly (passing).
// ============================================================================
__global__ __launch_bounds__(256) void finalize3_k(const float* __restrict__ part,
                                                   const float* __restrict__ rsum,
                                                   const float* __restrict__ mtb,
                                                   const float* __restrict__ lnw,
                                                   const float* __restrict__ skip,
                                                   const float* __restrict__ act,
                                                   const float* __restrict__ xin,
                                                   unsigned short* __restrict__ hshi,
                                                   unsigned short* __restrict__ hslo){
  const int sblk=blockIdx.x, head=blockIdx.y;
  const int bI=head>>2, nh=head&3;
  const int s0=sblk*32;
  const int t=threadIdx.x, row=t>>3, sub=t&7;
  __shared__ float red1[32][8], red2[32][8];
  __shared__ float mu_s[32], rs_s[32], inv_s[32];
  const size_t pbase=(size_t)head*2048+s0;
  const float* prow=part+(pbase+row)*336;
  float s1=0.f,s2=0.f;
  for(int c=sub;c<336;c+=8){ const float v=prow[c]; s1+=v; s2+=v*v; }
  red1[row][sub]=s1; red2[row][sub]=s2;
  __syncthreads();
  if(sub==0){
    float a1=0.f,a2=0.f;
#pragma unroll
    for(int j=0;j<8;j++){ a1+=red1[row][j]; a2+=red2[row][j]; }
    const float mt=mtb[(size_t)head*S_+s0+row];
    const float nn=fmaxf(fabsf(rsum[pbase+row]), expf(fminf(fmaxf(-mt,-60.f),60.f)));
    const float inv=1.f/(nn+1e-6f);
    const float mu=a1*inv/336.f;
    const float var=a2*inv*inv/336.f-mu*mu;
    inv_s[row]=inv; mu_s[row]=mu;
    rs_s[row]=rsqrtf(fmaxf(var,0.f)+1e-5f);
  }
  __syncthreads();
  const float inv=inv_s[row], mu=mu_s[row], rs=rs_s[row];
  const size_t gbs=(size_t)(bI*S_+s0+row);       // global row in hs matrix
  const float* arow=act+gbs*H_+nh*DH_;
  const float* zrow=xin+gbs*H2_+H_+nh*DH_;
  const float* srw=skip+nh*DH_;
  const float* lrw=lnw+nh*DH_;
  const size_t mtbase=(gbs>>4)*42;
  const int lbase=(int)(gbs&15);
  for(int c=sub;c<336;c+=8){
    const float hn=(prow[c]*inv-mu)*rs*lrw[c];
    const float val=(hn+srw[c]*arow[c])*siluf(zrow[c]);
    const int h=nh*DH_+c;
    const int kc=h>>5, quad=(h>>3)&3, j=h&7;
    const size_t slot=(mtbase+kc)*64+lbase+16*quad;
    const unsigned short hi=f2bf(val);
    hshi[slot*8+j]=hi;
    hslo[slot*8+j]=f2bf(val-bf2f(hi));
  }
}

// ============================================================================
extern "C" void kernel_launch(void* const* d_in, const int* in_sizes, int n_in,
                              void* d_out, int out_size, void* d_ws, size_t ws_size,
                              hipStream_t stream){
  float* ws=(float*)d_ws;
  int* flag=(int*)ws;

  float* igb  = ws+O_IGB;
  float* logfb= ws+O_LOGF;
  float* ab   = ws+O_AB;
  float* Mbuf = ws+O_MB;
  float* mtb  = ws+O_MTB;
  float* f_ck = ws+O_CK;
  float* f_cb = ws+O_CB;
  float* f_wq = ws+O_WQ;
  float* f_wk = ws+O_WK;
  float* f_wv = ws+O_WV;
  float* f_wig= ws+O_WIG;
  float* f_big= ws+O_BIG;
  float* f_wfg= ws+O_WFG;
  float* f_bfg= ws+O_BFG;
  float* f_lnw= ws+O_LNW;
  float* f_skp= ws+O_SKP;
  float* xin  = ws+O_XIN;
  float* act  = ws+O_ACT;
  float* qb   = ws+O_QB;
  float* kb   = ws+O_KB;
  float* vb   = ws+O_VB;

  unsigned short* xhi  =(unsigned short*)(ws+O_FX);   unsigned short* xlo  =xhi+N_X;
  unsigned short* wuphi=(unsigned short*)(ws+O_FWUP); unsigned short* wuplo=wuphi+N_WUP;
  unsigned short* wdnhi=(unsigned short*)(ws+O_FWDN); unsigned short* wdnlo=wdnhi+N_WDN;
  unsigned short* khi=(unsigned short*)(ws+O_FX);     // x/wup frags dead after up-gemm
  unsigned short* klo=khi+KSPLIT_SHORTS;
  unsigned short* vTf=(unsigned short*)(ws+O_HOUT);   // hout region: fully dead
  unsigned short* hshi=(unsigned short*)kb;    // kb region unused (K goes direct)
  unsigned short* hslo=hshi+N_BSH;
  float* partb=vb;                             // vb dead after vwprep (zeroed there)
  float* rsumb=igb;                            // igb dead after scan fold (zeroed there)

  detect_k<<<1,256,0,stream>>>((const unsigned short*)d_in[0],flag);
  // merged prep: x A-frags + Wup B-frags + 11 small weight conversions
  prepAB_k<<<2048+1344+226,256,0,stream>>>(d_in[0],d_in[1],flag,xhi,xlo,wuphi,wuplo,
                                           d_in[2],d_in[3],d_in[4],d_in[5],d_in[6],
                                           d_in[7],d_in[8],d_in[9],d_in[10],d_in[11],
                                           d_in[12],ws);
  // up-GEMM: xin = x @ Wup  (M=4096,K=1024 kcn=32, N=2688)
  gemm3_k<<<dim3(2688/128,4096/128),256,0,stream>>>(xhi,xlo,wuphi,wuplo,xin,nullptr,32,H2_);

  // fused conv+SiLU+qkv+gates + direct K-frag emit
  convqkvgates_k<<<BS_,384,0,stream>>>(xin,f_ck,f_cb,f_wq,f_wk,f_wv,
                                       f_wig,f_big,f_wfg,f_bfg,
                                       act,qb,vb,khi,klo,igb,logfb);
  // V frags + part-zero + Wdn frags + K-pad zero + scan (all independent)
  vwprep_k<<<512+672+64+8,256,0,stream>>>(vb,d_in[13],flag,vTf,wdnhi,wdnlo,
                                          khi,klo,partb,
                                          igb,logfb,ab,Mbuf,mtb);
  // mLSTM v12 (proven): 256 blocks x 512 thr
  mlstm6_k<<<256,512,0,stream>>>(qb,khi,klo,vTf,ab,Mbuf,partb,rsumb);
  // finalize v3: groupnorm + h_state + DIRECT A-frag emit
  finalize3_k<<<dim3(S_/32,B_*NH_),256,0,stream>>>(partb,rsumb,mtb,f_lnw,f_skp,act,xin,
                                                   hshi,hslo);
  // down-GEMM: out = hs @ Wdn (128x128 tile, gemm3 — 128x64 variant regressed)
  gemm3_k<<<dim3(1024/128,4096/128),256,0,stream>>>(hshi,hslo,wdnhi,wdnlo,d_out,flag,42,E_);
}